// Round 1
// baseline (1751.948 us; speedup 1.0000x reference)
//
#include <hip/hip_runtime.h>
#include <math.h>

// Problem constants (B,S,D,H from reference)
#define B_  2
#define S_  2048
#define D_  1024
#define H_  16
#define HD_ 64
#define M_  (B_*S_)   // 4096 rows in the flattened [B*S, D] view

// ---------------------------------------------------------------------------
// Kernel 0: RoPE cos/sin tables, computed in fp64 once per call.
// cos_t/sin_t layout: [S][32], index j in 0..31 = frequency index (c & 31).
// ---------------------------------------------------------------------------
__global__ void rope_table_kernel(float* __restrict__ cos_t, float* __restrict__ sin_t)
{
    int i = blockIdx.x * 256 + threadIdx.x;     // 0 .. S*32-1
    if (i >= S_ * 32) return;
    int s = i >> 5;
    int j = i & 31;
    double inv = pow(10000.0, -(double)j / 32.0);   // 10000^(-2j/64)
    double ang = (double)s * inv;
    cos_t[i] = (float)cos(ang);
    sin_t[i] = (float)sin(ang);
}

// ---------------------------------------------------------------------------
// Shared GEMM core: computes C[m0:m0+64, e0:e0+64] = A[m,:] . B[e,:]^T
// (torch Linear convention: y = x @ W.T; both A and W are row-major with K
// contiguous). Result left in Cs (LDS) for the caller's epilogue.
// Block = 256 threads (16x16 micro-grid, 4x4 acc per thread), BK = 16.
// ---------------------------------------------------------------------------
__device__ __forceinline__ void gemm_tile_64x64(
    const float* __restrict__ A, const float* __restrict__ Bm,
    int m0, int e0,
    float (*As)[68], float (*Bs)[68], float (*Cs)[68], int tid)
{
    int tr = tid >> 4, tc = tid & 15;
    int lr = tid >> 2, lq = tid & 3;
    float acc[4][4];
#pragma unroll
    for (int i = 0; i < 4; i++)
#pragma unroll
        for (int j = 0; j < 4; j++) acc[i][j] = 0.f;

    for (int k0 = 0; k0 < D_; k0 += 16) {
        float4 a = *(const float4*)&A [(size_t)(m0 + lr) * D_ + k0 + lq * 4];
        float4 b = *(const float4*)&Bm[(size_t)(e0 + lr) * D_ + k0 + lq * 4];
        As[lq*4+0][lr] = a.x; As[lq*4+1][lr] = a.y; As[lq*4+2][lr] = a.z; As[lq*4+3][lr] = a.w;
        Bs[lq*4+0][lr] = b.x; Bs[lq*4+1][lr] = b.y; Bs[lq*4+2][lr] = b.z; Bs[lq*4+3][lr] = b.w;
        __syncthreads();
#pragma unroll
        for (int kk = 0; kk < 16; kk++) {
            float4 a4 = *(const float4*)&As[kk][tr * 4];
            float4 b4 = *(const float4*)&Bs[kk][tc * 4];
            float av[4] = {a4.x, a4.y, a4.z, a4.w};
            float bv[4] = {b4.x, b4.y, b4.z, b4.w};
#pragma unroll
            for (int i = 0; i < 4; i++)
#pragma unroll
                for (int j = 0; j < 4; j++) acc[i][j] += av[i] * bv[j];
        }
        __syncthreads();
    }
#pragma unroll
    for (int i = 0; i < 4; i++)
#pragma unroll
        for (int j = 0; j < 4; j++) Cs[tr*4+i][tc*4+j] = acc[i][j];
    __syncthreads();
}

// ---------------------------------------------------------------------------
// Kernel 1: QKV projection + RoPE. grid = (M/64, 48): y = proj*16 + head.
// Each 64-wide column tile is exactly one head. RoPE partner col = c ^ 32.
// Output layout [B, H, S, HD].
// ---------------------------------------------------------------------------
__global__ __launch_bounds__(256, 2) void qkv_rope_kernel(
    const float* __restrict__ X,
    const float* __restrict__ Wq, const float* __restrict__ Wk, const float* __restrict__ Wv,
    const float* __restrict__ cos_t, const float* __restrict__ sin_t,
    float* __restrict__ Q, float* __restrict__ K, float* __restrict__ V)
{
    __shared__ float As[16][68], Bs[16][68], Cs[64][68];
    int mt = blockIdx.x, gy = blockIdx.y;
    int proj = gy >> 4;          // 0=Q 1=K 2=V (uniform per block)
    int h    = gy & 15;
    const float* W = (proj == 0) ? Wq : (proj == 1) ? Wk : Wv;
    float* dst     = (proj == 0) ? Q  : (proj == 1) ? K  : V;
    int m0 = mt * 64, e0 = h * 64;

    gemm_tile_64x64(X, W, m0, e0, As, Bs, Cs, threadIdx.x);

#pragma unroll
    for (int k = 0; k < 4; k++) {
        int f  = threadIdx.x + k * 256;   // 0..1023 -> 64 rows x 16 float4
        int r  = f >> 4;
        int c0 = (f & 15) * 4;
        int m  = m0 + r;
        int b  = m >> 11;                  // /S_
        int s  = m & 2047;                 // %S_
        float4 v0 = *(const float4*)&Cs[r][c0];
        float4 res;
        if (proj == 2) {
            res = v0;
        } else {
            float4 vp = *(const float4*)&Cs[r][c0 ^ 32];
            float vin[4] = {v0.x, v0.y, v0.z, v0.w};
            float vpr[4] = {vp.x, vp.y, vp.z, vp.w};
            float out[4];
#pragma unroll
            for (int cc = 0; cc < 4; cc++) {
                int c  = c0 + cc;
                int j32 = c & 31;
                float cs = cos_t[s * 32 + j32];
                float sn = sin_t[s * 32 + j32];
                float rot = (c < 32) ? -vpr[cc] : vpr[cc];   // rotate_half
                out[cc] = vin[cc] * cs + rot * sn;
            }
            res = make_float4(out[0], out[1], out[2], out[3]);
        }
        *(float4*)&dst[(((size_t)b * H_ + h) * S_ + s) * HD_ + c0] = res;
    }
}

// ---------------------------------------------------------------------------
// Kernel 2: flash attention, fp32, one thread per query row.
// grid = (S/256, B*H), block = 256. K/V tiles of KT keys staged in LDS; all
// lanes read the same LDS address per (j,d) -> broadcast (conflict-free).
// Online softmax (m, l running). Output layout [B, S, H, HD] == [B,S,D].
// ---------------------------------------------------------------------------
#define KT 16
__global__ __launch_bounds__(256, 2) void flash_attn_kernel(
    const float* __restrict__ Q, const float* __restrict__ K, const float* __restrict__ V,
    const int* __restrict__ mask, float* __restrict__ O)
{
    __shared__ float Ks[KT][HD_];
    __shared__ float Vs[KT][HD_];
    __shared__ int   ms[KT];
    int bh = blockIdx.y;
    int b = bh >> 4, h = bh & 15;
    int q = blockIdx.x * 256 + threadIdx.x;    // 0..2047

    const float* Qr = Q + ((size_t)bh * S_ + q) * HD_;
    float qreg[HD_];
#pragma unroll
    for (int d = 0; d < HD_; d += 4) {
        float4 t = *(const float4*)&Qr[d];
        qreg[d] = t.x; qreg[d+1] = t.y; qreg[d+2] = t.z; qreg[d+3] = t.w;
    }
    float o[HD_];
#pragma unroll
    for (int d = 0; d < HD_; d++) o[d] = 0.f;
    float mx = -3.0e38f, l = 0.f;

    const float* Kb = K + (size_t)bh * S_ * HD_;
    const float* Vb = V + (size_t)bh * S_ * HD_;
    const int*   mb = mask + b * S_;

    for (int k0 = 0; k0 < S_; k0 += KT) {
        __syncthreads();
        {
            int f  = threadIdx.x;          // 256 float4 = KT*HD_/4
            int r  = f >> 4;
            int c4 = (f & 15) * 4;
            *(float4*)&Ks[r][c4] = *(const float4*)&Kb[(size_t)(k0 + r) * HD_ + c4];
            *(float4*)&Vs[r][c4] = *(const float4*)&Vb[(size_t)(k0 + r) * HD_ + c4];
            if (threadIdx.x < KT) ms[threadIdx.x] = mb[k0 + threadIdx.x];
        }
        __syncthreads();

        float sc[KT];
        float tmax = -3.0e38f;
#pragma unroll
        for (int j = 0; j < KT; j++) {
            float s = 0.f;
#pragma unroll
            for (int d = 0; d < HD_; d += 4) {
                float4 kv = *(const float4*)&Ks[j][d];
                s += qreg[d] * kv.x + qreg[d+1] * kv.y + qreg[d+2] * kv.z + qreg[d+3] * kv.w;
            }
            s *= 0.125f;                       // HD^-0.5
            s = ms[j] ? s : -3.0e38f;          // attention_mask
            sc[j] = s;
            tmax = fmaxf(tmax, s);
        }
        float mnew  = fmaxf(mx, tmax);
        float scale = __expf(mx - mnew);       // 0 when mx == -3e38 and mnew finite
        l *= scale;
#pragma unroll
        for (int d = 0; d < HD_; d++) o[d] *= scale;
#pragma unroll
        for (int j = 0; j < KT; j++) {
            float p = __expf(sc[j] - mnew);
            l += p;
#pragma unroll
            for (int d = 0; d < HD_; d += 4) {
                float4 vv = *(const float4*)&Vs[j][d];
                o[d]   += p * vv.x; o[d+1] += p * vv.y;
                o[d+2] += p * vv.z; o[d+3] += p * vv.w;
            }
        }
        mx = mnew;
    }

    float inv = 1.0f / l;
    float* Or = O + (((size_t)(b * S_ + q)) * H_ + h) * HD_;
#pragma unroll
    for (int d = 0; d < HD_; d += 4) {
        float4 t = make_float4(o[d] * inv, o[d+1] * inv, o[d+2] * inv, o[d+3] * inv);
        *(float4*)&Or[d] = t;
    }
}

// ---------------------------------------------------------------------------
// Kernel 3: output projection, plain GEMM to d_out ([B,S,D] row-major).
// ---------------------------------------------------------------------------
__global__ __launch_bounds__(256, 2) void out_proj_kernel(
    const float* __restrict__ A, const float* __restrict__ W, float* __restrict__ out)
{
    __shared__ float As[16][68], Bs[16][68], Cs[64][68];
    int m0 = blockIdx.x * 64, e0 = blockIdx.y * 64;
    gemm_tile_64x64(A, W, m0, e0, As, Bs, Cs, threadIdx.x);
#pragma unroll
    for (int k = 0; k < 4; k++) {
        int f  = threadIdx.x + k * 256;
        int r  = f >> 4;
        int q4 = f & 15;
        *(float4*)&out[(size_t)(m0 + r) * D_ + e0 + q4 * 4] = *(const float4*)&Cs[r][q4 * 4];
    }
}

// ---------------------------------------------------------------------------
// Launch. Workspace layout (floats):
//   Q [B,H,S,HD]  4M | K 4M | V 4M | attnO [B,S,D] 4M | cosT 64K | sinT 64K
// Total = 67,633,152 bytes (~64.5 MB) — must fit ws_size.
// ---------------------------------------------------------------------------
extern "C" void kernel_launch(void* const* d_in, const int* in_sizes, int n_in,
                              void* d_out, int out_size, void* d_ws, size_t ws_size,
                              hipStream_t stream)
{
    const float* X    = (const float*)d_in[0];
    const int*   mask = (const int*)  d_in[1];
    const float* Wq   = (const float*)d_in[2];
    const float* Wk   = (const float*)d_in[3];
    const float* Wv   = (const float*)d_in[4];
    const float* Wo   = (const float*)d_in[5];
    float* out = (float*)d_out;

    float* ws   = (float*)d_ws;
    const size_t PER = (size_t)B_ * H_ * S_ * HD_;   // 4,194,304
    float* Qw   = ws;
    float* Kw   = Qw + PER;
    float* Vw   = Kw + PER;
    float* Ow   = Vw + PER;
    float* cosT = Ow + PER;
    float* sinT = cosT + S_ * 32;

    rope_table_kernel<<<(S_ * 32) / 256, 256, 0, stream>>>(cosT, sinT);
    qkv_rope_kernel<<<dim3(M_ / 64, 48), 256, 0, stream>>>(X, Wq, Wk, Wv, cosT, sinT, Qw, Kw, Vw);
    flash_attn_kernel<<<dim3(S_ / 256, B_ * H_), 256, 0, stream>>>(Qw, Kw, Vw, mask, Ow);
    out_proj_kernel<<<dim3(M_ / 64, D_ / 64), 256, 0, stream>>>(Ow, Wo, out);
}